// Round 1
// baseline (468.986 us; speedup 1.0000x reference)
//
#include <hip/hip_runtime.h>
#include <math.h>

#define B_ 32
#define H_ 112
#define W_ 112
#define C_ 128
#define R_ 2048
#define HW_ (H_ * W_)      // 12544
#define C4_ (C_ / 4)       // 32 float4 per pixel
#define POOL_BLOCKS_PER_B 16

// ---------------------------------------------------------------------------
// Kernel 1: global average pool (partial sums -> atomicAdd into s[B,C])
// s must be zeroed before launch (done via hipMemsetAsync in kernel_launch).
// Each block: one (batch, pixel-chunk). Wave reads 1KB contiguous (2 pixels).
// ---------------------------------------------------------------------------
__global__ __launch_bounds__(256) void pool_kernel(const float4* __restrict__ x,
                                                   float* __restrict__ s) {
    const int b     = blockIdx.x;       // 0..31
    const int pb    = blockIdx.y;       // 0..15
    const int t     = threadIdx.x;      // 0..255
    const int lane4 = t & 31;           // float4 slot within pixel (channel/4)
    const int prow  = t >> 5;           // 0..7 pixel offset within iteration

    const int pixels_per_block = HW_ / POOL_BLOCKS_PER_B;  // 784
    const int p0 = pb * pixels_per_block;
    const float4* xb = x + (size_t)b * HW_ * C4_;

    float4 acc = make_float4(0.f, 0.f, 0.f, 0.f);
    for (int p = p0 + prow; p < p0 + pixels_per_block; p += 8) {
        float4 v = xb[(size_t)p * C4_ + lane4];
        acc.x += v.x; acc.y += v.y; acc.z += v.z; acc.w += v.w;
    }

    __shared__ float4 red[256];
    red[t] = acc;
    __syncthreads();
    if (t < 32) {
        float4 a = red[t];
#pragma unroll
        for (int k = 1; k < 8; ++k) {
            float4 v = red[t + 32 * k];
            a.x += v.x; a.y += v.y; a.z += v.z; a.w += v.w;
        }
        float* sb = s + b * C_ + t * 4;
        atomicAdd(sb + 0, a.x);
        atomicAdd(sb + 1, a.y);
        atomicAdd(sb + 2, a.z);
        atomicAdd(sb + 3, a.w);
    }
}

// ---------------------------------------------------------------------------
// Kernel 2: h[b][r] = gelu_tanh(mean_s[b] . w1[:,r] + b1[r])
// grid = B*8 blocks of 256 (8 r-blocks per batch). w1 reads coalesced over r.
// ---------------------------------------------------------------------------
__global__ __launch_bounds__(256) void fc1_kernel(const float* __restrict__ s,
                                                  const float* __restrict__ w1,
                                                  const float* __restrict__ b1,
                                                  float* __restrict__ h) {
    const int b  = blockIdx.x >> 3;
    const int rb = blockIdx.x & 7;
    const int r  = rb * 256 + threadIdx.x;

    __shared__ float sl[C_];
    if (threadIdx.x < C_)
        sl[threadIdx.x] = s[b * C_ + threadIdx.x] * (1.0f / (float)HW_);
    __syncthreads();

    float acc = b1[r];
#pragma unroll 8
    for (int c = 0; c < C_; ++c)
        acc += sl[c] * w1[(size_t)c * R_ + r];

    // tanh-approx GELU (jax.nn.gelu default): 0.5x(1+tanh(sqrt(2/pi)(x+0.044715x^3)))
    const float xv = acc;
    const float tn = tanhf(0.7978845608028654f * (xv + 0.044715f * xv * xv * xv));
    h[(size_t)b * R_ + r] = 0.5f * xv * (1.0f + tn);
}

// ---------------------------------------------------------------------------
// Kernel 3: g[b][c] = sigmoid(h[b] . w2[:,c] + b2[c])
// One block per batch. h staged in LDS (same-addr broadcast reads, free).
// w2 rows read coalesced over c. 2-way K-split + LDS reduce.
// ---------------------------------------------------------------------------
__global__ __launch_bounds__(256) void fc2_kernel(const float* __restrict__ h,
                                                  const float* __restrict__ w2,
                                                  const float* __restrict__ b2,
                                                  float* __restrict__ g) {
    const int b    = blockIdx.x;
    const int t    = threadIdx.x;
    const int c    = t & 127;
    const int half = t >> 7;

    __shared__ float hl[R_];
    for (int i = t; i < R_; i += 256) hl[i] = h[(size_t)b * R_ + i];
    __syncthreads();

    float acc = 0.f;
    const int r0 = half * (R_ / 2);
#pragma unroll 8
    for (int r = r0; r < r0 + R_ / 2; ++r)
        acc += hl[r] * w2[(size_t)r * C_ + c];

    __shared__ float part[256];
    part[t] = acc;
    __syncthreads();
    if (t < 128) {
        const float v = part[t] + part[t + 128] + b2[t];
        g[b * C_ + t] = 1.0f / (1.0f + expf(-v));
    }
}

// ---------------------------------------------------------------------------
// Kernel 4: out = x * g (broadcast over spatial). float4 grid-stride.
// Stride is a multiple of 32 float4s, so each thread's channel slot (c4) is
// loop-invariant -> gate loaded exactly once per thread.
// ---------------------------------------------------------------------------
__global__ __launch_bounds__(256) void scale_kernel(const float4* __restrict__ x,
                                                    const float4* __restrict__ g,
                                                    float4* __restrict__ out) {
    const int b  = blockIdx.x;
    const int t  = threadIdx.x;
    const int c4 = t & 31;

    const float4 gv = g[b * C4_ + c4];
    const size_t base = (size_t)b * HW_ * C4_;
    const int total = HW_ * C4_;  // 401408 float4 per batch
    const int stride = gridDim.y * 256;

    for (int i = blockIdx.y * 256 + t; i < total; i += stride) {
        float4 v = x[base + i];
        v.x *= gv.x; v.y *= gv.y; v.z *= gv.z; v.w *= gv.w;
        out[base + i] = v;
    }
}

extern "C" void kernel_launch(void* const* d_in, const int* in_sizes, int n_in,
                              void* d_out, int out_size, void* d_ws, size_t ws_size,
                              hipStream_t stream) {
    const float* x  = (const float*)d_in[0];
    const float* w1 = (const float*)d_in[1];
    const float* b1 = (const float*)d_in[2];
    const float* w2 = (const float*)d_in[3];
    const float* b2 = (const float*)d_in[4];
    float* out = (float*)d_out;

    // workspace layout: s[B*C] | h[B*R] | g[B*C]  (~288 KB)
    float* s = (float*)d_ws;
    float* h = s + B_ * C_;
    float* g = h + B_ * R_;

    // s is accumulated via atomics -> must start at zero (ws is poisoned 0xAA)
    hipMemsetAsync(s, 0, B_ * C_ * sizeof(float), stream);

    pool_kernel<<<dim3(B_, POOL_BLOCKS_PER_B), 256, 0, stream>>>((const float4*)x, s);
    fc1_kernel<<<B_ * 8, 256, 0, stream>>>(s, w1, b1, h);
    fc2_kernel<<<B_, 256, 0, stream>>>(h, w2, b2, g);
    scale_kernel<<<dim3(B_, 64), 256, 0, stream>>>((const float4*)x, (const float4*)g,
                                                   (float4*)out);
}

// Round 2
// 422.239 us; speedup vs baseline: 1.1107x; 1.1107x over previous
//
#include <hip/hip_runtime.h>
#include <math.h>

#define B_ 32
#define H_ 112
#define W_ 112
#define C_ 128
#define R_ 2048
#define HW_ (H_ * W_)      // 12544
#define C4_ (C_ / 4)       // 32 float4 per pixel
#define PB_ 32             // pool blocks per batch

typedef float f32x4_t __attribute__((ext_vector_type(4)));

// ---------------------------------------------------------------------------
// Kernel 1: pool partials. grid (B, PB_). Each block reduces 392 pixels and
// writes one 128-float partial vector (no atomics, no memset needed).
// Wave reads 1 KB contiguous (2 pixels of 128ch fp32).
// ---------------------------------------------------------------------------
__global__ __launch_bounds__(256) void pool_kernel(const float4* __restrict__ x,
                                                   float4* __restrict__ part) {
    const int b     = blockIdx.x;       // 0..31
    const int pb    = blockIdx.y;       // 0..PB_-1
    const int t     = threadIdx.x;      // 0..255
    const int lane4 = t & 31;           // float4 slot (channel/4)
    const int prow  = t >> 5;           // 0..7

    const int pixels_per_block = HW_ / PB_;  // 392
    const int p0 = pb * pixels_per_block;
    const float4* xb = x + (size_t)b * HW_ * C4_;

    float4 acc = make_float4(0.f, 0.f, 0.f, 0.f);
    for (int p = p0 + prow; p < p0 + pixels_per_block; p += 8) {
        float4 v = xb[(size_t)p * C4_ + lane4];
        acc.x += v.x; acc.y += v.y; acc.z += v.z; acc.w += v.w;
    }

    __shared__ float4 red[256];
    red[t] = acc;
    __syncthreads();
    if (t < 32) {
        float4 a = red[t];
#pragma unroll
        for (int k = 1; k < 8; ++k) {
            float4 v = red[t + 32 * k];
            a.x += v.x; a.y += v.y; a.z += v.z; a.w += v.w;
        }
        part[((size_t)b * PB_ + pb) * C4_ + t] = a;
    }
}

// ---------------------------------------------------------------------------
// Kernel 2: reduce partials -> mean, then h[b][r] = gelu_tanh(s.w1[:,r]+b1[r])
// grid = B*8 blocks of 256. w1 reads coalesced over r. Partial-reduce is
// redundant across the 8 r-blocks of a batch but costs ~16 KB of L2 reads.
// ---------------------------------------------------------------------------
__global__ __launch_bounds__(256) void fc1_kernel(const float4* __restrict__ part,
                                                  const float* __restrict__ w1,
                                                  const float* __restrict__ b1,
                                                  float* __restrict__ h) {
    const int b  = blockIdx.x >> 3;
    const int rb = blockIdx.x & 7;
    const int r  = rb * 256 + threadIdx.x;
    const int t  = threadIdx.x;

    __shared__ float sl[C_];
    if (t < 32) {
        float4 a = make_float4(0.f, 0.f, 0.f, 0.f);
#pragma unroll 8
        for (int k = 0; k < PB_; ++k) {
            float4 v = part[((size_t)b * PB_ + k) * C4_ + t];
            a.x += v.x; a.y += v.y; a.z += v.z; a.w += v.w;
        }
        const float inv = 1.0f / (float)HW_;
        sl[t * 4 + 0] = a.x * inv;
        sl[t * 4 + 1] = a.y * inv;
        sl[t * 4 + 2] = a.z * inv;
        sl[t * 4 + 3] = a.w * inv;
    }
    __syncthreads();

    float acc = b1[r];
#pragma unroll 8
    for (int c = 0; c < C_; ++c)
        acc += sl[c] * w1[(size_t)c * R_ + r];

    // tanh-approx GELU: 0.5x(1+tanh(sqrt(2/pi)(x+0.044715x^3)))
    const float xv = acc;
    const float tn = tanhf(0.7978845608028654f * (xv + 0.044715f * xv * xv * xv));
    h[(size_t)b * R_ + r] = 0.5f * xv * (1.0f + tn);
}

// ---------------------------------------------------------------------------
// Kernel 3: g[b][c] = sigmoid(h[b] . w2[:,c] + b2[c])
// One block per batch. h in LDS (2-distinct-addr broadcast per wave, free).
// w2 read as float4 (1 KB/wave), 8-way K-split + LDS reduce.
// ---------------------------------------------------------------------------
__global__ __launch_bounds__(256) void fc2_kernel(const float* __restrict__ h,
                                                  const float4* __restrict__ w2,
                                                  const float* __restrict__ b2,
                                                  float4* __restrict__ g) {
    const int b     = blockIdx.x;
    const int t     = threadIdx.x;
    const int c4    = t & 31;   // float4 column group
    const int slice = t >> 5;   // 0..7 K-slice

    __shared__ float hl[R_];
    for (int i = t; i < R_; i += 256) hl[i] = h[(size_t)b * R_ + i];
    __syncthreads();

    float4 acc = make_float4(0.f, 0.f, 0.f, 0.f);
    const int r0 = slice * (R_ / 8);
#pragma unroll 4
    for (int r = r0; r < r0 + R_ / 8; ++r) {
        const float hv = hl[r];
        float4 w = w2[(size_t)r * C4_ + c4];
        acc.x += hv * w.x; acc.y += hv * w.y; acc.z += hv * w.z; acc.w += hv * w.w;
    }

    __shared__ float4 partl[256];
    partl[t] = acc;
    __syncthreads();
    if (t < 32) {
        float4 a = partl[t];
#pragma unroll
        for (int k = 1; k < 8; ++k) {
            float4 v = partl[t + 32 * k];
            a.x += v.x; a.y += v.y; a.z += v.z; a.w += v.w;
        }
        a.x += b2[t * 4 + 0]; a.y += b2[t * 4 + 1];
        a.z += b2[t * 4 + 2]; a.w += b2[t * 4 + 3];
        float4 gv;
        gv.x = 1.0f / (1.0f + expf(-a.x));
        gv.y = 1.0f / (1.0f + expf(-a.y));
        gv.z = 1.0f / (1.0f + expf(-a.z));
        gv.w = 1.0f / (1.0f + expf(-a.w));
        g[(size_t)b * C4_ + t] = gv;
    }
}

// ---------------------------------------------------------------------------
// Kernel 4: out = x * g. float4 grid-stride; stride % 32 == 0 so the gate is
// loop-invariant per thread. NON-TEMPORAL stores for out: out is never
// re-read, and keeping it out of L2/L3 preserves x's L3 residency (x fits
// the 256 MB Infinity Cache) so this pass's x-read hits L3, not HBM.
// ---------------------------------------------------------------------------
__global__ __launch_bounds__(256) void scale_kernel(const float4* __restrict__ x,
                                                    const float4* __restrict__ g,
                                                    float4* __restrict__ out) {
    const int b  = blockIdx.x;
    const int t  = threadIdx.x;
    const int c4 = t & 31;

    const float4 gv = g[(size_t)b * C4_ + c4];
    const size_t base = (size_t)b * HW_ * C4_;
    const int total = HW_ * C4_;  // 401408 float4 per batch
    const int stride = gridDim.y * 256;

    for (int i = blockIdx.y * 256 + t; i < total; i += stride) {
        float4 v = x[base + i];
        f32x4_t o;
        o.x = v.x * gv.x; o.y = v.y * gv.y; o.z = v.z * gv.z; o.w = v.w * gv.w;
        __builtin_nontemporal_store(o, (f32x4_t*)&out[base + i]);
    }
}

extern "C" void kernel_launch(void* const* d_in, const int* in_sizes, int n_in,
                              void* d_out, int out_size, void* d_ws, size_t ws_size,
                              hipStream_t stream) {
    const float* x  = (const float*)d_in[0];
    const float* w1 = (const float*)d_in[1];
    const float* b1 = (const float*)d_in[2];
    const float* w2 = (const float*)d_in[3];
    const float* b2 = (const float*)d_in[4];
    float* out = (float*)d_out;

    // workspace: part[B*PB_*C] | h[B*R] | g[B*C]   (~800 KB)
    float* part = (float*)d_ws;
    float* h    = part + B_ * PB_ * C_;
    float* g    = h + B_ * R_;

    pool_kernel<<<dim3(B_, PB_), 256, 0, stream>>>((const float4*)x, (float4*)part);
    fc1_kernel<<<B_ * 8, 256, 0, stream>>>((const float4*)part, w1, b1, h);
    fc2_kernel<<<B_, 256, 0, stream>>>(h, (const float4*)w2, b2, (float4*)g);
    scale_kernel<<<dim3(B_, 64), 256, 0, stream>>>((const float4*)x, (const float4*)g,
                                                   (float4*)out);
}